// Round 3
// baseline (2224.272 us; speedup 1.0000x reference)
//
#include <hip/hip_runtime.h>

// MaxUnpooling2D scatter-add, batch-windowed for Infinity-Cache residency.
// B=8; per-batch input = 2^22 elems (16 MiB f32 + 16 MiB i32);
// per-batch output window = 2^24 elems = 64 MiB (fits in 256 MiB MALL).
// Global flat index g = (b<<24) + idx, idx < 2^24 -> batch == 64MiB window.

#define BATCHES 8
#define IN_PER_BATCH  (1 << 22)   // elements
#define OUT_PER_BATCH (1 << 24)   // elements

// Native clang vector types (required by __builtin_nontemporal_load).
typedef float fx4 __attribute__((ext_vector_type(4)));
typedef int   ix4 __attribute__((ext_vector_type(4)));

// Zero one batch's output window with vectorized regular stores
// (want the zeros resident at the coherence point for the scatter pass).
__global__ __launch_bounds__(256) void zero_window(fx4* __restrict__ out4, int n4)
{
    int t = blockIdx.x * blockDim.x + threadIdx.x;
    if (t < n4) {
        out4[t] = (fx4){0.f, 0.f, 0.f, 0.f};
    }
}

// Scatter one batch: atomics confined to a 64 MiB window.
// Streams (val/idx) read nontemporally to avoid evicting the window.
__global__ __launch_bounds__(256) void scatter_batch(
    const fx4* __restrict__ in4,
    const ix4* __restrict__ idx4,
    float* __restrict__ outb,
    int n4)
{
    int t = blockIdx.x * blockDim.x + threadIdx.x;
    if (t >= n4) return;

    fx4 v  = __builtin_nontemporal_load(in4 + t);
    ix4 id = __builtin_nontemporal_load(idx4 + t);

    atomicAdd(outb + id.x, v.x);
    atomicAdd(outb + id.y, v.y);
    atomicAdd(outb + id.z, v.z);
    atomicAdd(outb + id.w, v.w);
}

extern "C" void kernel_launch(void* const* d_in, const int* in_sizes, int n_in,
                              void* d_out, int out_size, void* d_ws, size_t ws_size,
                              hipStream_t stream) {
    const float* in  = (const float*)d_in[0];
    const int*   idx = (const int*)d_in[1];
    float*       out = (float*)d_out;

    const int zn4 = OUT_PER_BATCH / 4;            // 2^22 fx4 per window
    const int sn4 = IN_PER_BATCH / 4;             // 2^20 vec4 groups per batch
    const int zgrid = zn4 / 256;                  // 16384 blocks
    const int sgrid = sn4 / 256;                  // 4096 blocks

    for (int b = 0; b < BATCHES; ++b) {
        float* outb = out + (size_t)b * OUT_PER_BATCH;
        const fx4* in4  = (const fx4*)(in  + (size_t)b * IN_PER_BATCH);
        const ix4* idx4 = (const ix4*)(idx + (size_t)b * IN_PER_BATCH);

        // 1) zero this batch's 64 MiB window (lands in MALL at dispatch end)
        zero_window<<<zgrid, 256, 0, stream>>>((fx4*)outb, zn4);
        // 2) scatter this batch's atomics into the L3-resident window
        scatter_batch<<<sgrid, 256, 0, stream>>>(in4, idx4, outb, sn4);
    }
}

// Round 4
// 1234.854 us; speedup vs baseline: 1.8012x; 1.8012x over previous
//
#include <hip/hip_runtime.h>
#include <stdint.h>

// MaxUnpooling2D scatter-add WITHOUT global data atomics.
// Evidence (R1/R3): fp32 global atomics run at a fixed memory-side RMW rate
// (~20 G/s, 32B write-through each) regardless of cache residency.
// Plan: bin (idx,val) pairs by 32KiB output region, then per-region LDS
// accumulate + coalesced output write.
//
// B=8, per-batch in = 2^22 elems, per-batch out = 2^24 floats.
// Region = 2^13 floats (32 KiB). Buckets: 2048/batch, 16384 total.
// Expected pairs/bucket = 2^22/2048 = 2048; capacity 4096 (2x mean).

#define LOG2_REGION   13
#define REGION        (1 << LOG2_REGION)          // 8192 floats
#define NB_PER_BATCH  (1 << (24 - LOG2_REGION))   // 2048 buckets/batch
#define NBUCKETS      (8 * NB_PER_BATCH)          // 16384
#define CHUNK         65536                       // pairs per bin-block
#define GRID1         (8 * (1 << 22) / CHUNK)     // 512 blocks
#define BLOCK1        512

// ---------------- Pass 1: bin pairs into fixed-capacity bucket segments ----
__global__ __launch_bounds__(BLOCK1) void bin_pairs(
    const int*   __restrict__ idx,
    const float* __restrict__ val,
    int*         __restrict__ counters,   // [NBUCKETS], pre-zeroed
    uint64_t*    __restrict__ pairs,      // [NBUCKETS * cap]
    int cap)
{
    __shared__ int hist[NB_PER_BATCH];
    __shared__ int base[NB_PER_BATCH];

    const int tid = threadIdx.x;
    const long long start = (long long)blockIdx.x * CHUNK;  // chunk is within one batch
    const int batch = (int)(start >> 22);
    const int4*   idx4 = (const int4*)(idx + start);
    const float4* val4 = (const float4*)(val + start);

    for (int i = tid; i < NB_PER_BATCH; i += BLOCK1) hist[i] = 0;
    __syncthreads();

    const int ITER = CHUNK / 4 / BLOCK1;   // 32
    for (int it = 0; it < ITER; ++it) {
        int4 v = idx4[it * BLOCK1 + tid];
        atomicAdd(&hist[v.x >> LOG2_REGION], 1);
        atomicAdd(&hist[v.y >> LOG2_REGION], 1);
        atomicAdd(&hist[v.z >> LOG2_REGION], 1);
        atomicAdd(&hist[v.w >> LOG2_REGION], 1);
    }
    __syncthreads();

    // Reserve contiguous per-(block,bucket) segments in the global buckets.
    int* gc = counters + batch * NB_PER_BATCH;
    for (int i = tid; i < NB_PER_BATCH; i += BLOCK1) {
        int h = hist[i];
        base[i] = h ? atomicAdd(&gc[i], h) : 0;
        hist[i] = 0;                       // reuse as local cursor
    }
    __syncthreads();

    uint64_t* pb = pairs + (uint64_t)batch * NB_PER_BATCH * (uint64_t)cap;
    for (int it = 0; it < ITER; ++it) {
        int4   vi = idx4[it * BLOCK1 + tid];
        float4 vv = val4[it * BLOCK1 + tid];
        int ia[4] = {vi.x, vi.y, vi.z, vi.w};
        float fa[4] = {vv.x, vv.y, vv.z, vv.w};
        #pragma unroll
        for (int k = 0; k < 4; ++k) {
            int bucket = ia[k] >> LOG2_REGION;
            int slot = base[bucket] + atomicAdd(&hist[bucket], 1);
            if (slot < cap) {
                uint64_t p = (uint64_t)(uint32_t)(ia[k] & (REGION - 1))
                           | ((uint64_t)__float_as_uint(fa[k]) << 32);
                pb[(uint64_t)bucket * cap + slot] = p;
            }
        }
    }
}

// ---------------- Pass 2: per-bucket LDS accumulate + coalesced write ------
__global__ __launch_bounds__(256) void accumulate(
    const uint64_t* __restrict__ pairs,
    const int*      __restrict__ counters,
    float*          __restrict__ out,
    int cap)
{
    __shared__ float acc[REGION];          // 32 KiB
    const int b = blockIdx.x;              // bucket id == output region id
    const int tid = threadIdx.x;

    float4* acc4 = (float4*)acc;
    for (int i = tid; i < REGION / 4; i += 256)
        acc4[i] = make_float4(0.f, 0.f, 0.f, 0.f);
    __syncthreads();

    int n = counters[b];
    if (n > cap) n = cap;
    const uint64_t* p = pairs + (uint64_t)b * cap;
    for (int i = tid; i < n; i += 256) {
        uint64_t v = p[i];
        atomicAdd(&acc[(int)(v & (REGION - 1))],
                  __uint_as_float((uint32_t)(v >> 32)));   // ds_add_f32
    }
    __syncthreads();

    // out offset: batch*2^24 + region*2^13 == b * 2^13  (b = batch*2048+region)
    float4* o4 = (float4*)(out + ((long long)b << LOG2_REGION));
    for (int i = tid; i < REGION / 4; i += 256)
        o4[i] = acc4[i];
}

extern "C" void kernel_launch(void* const* d_in, const int* in_sizes, int n_in,
                              void* d_out, int out_size, void* d_ws, size_t ws_size,
                              hipStream_t stream) {
    const float* in  = (const float*)d_in[0];
    const int*   idx = (const int*)d_in[1];
    float*       out = (float*)d_out;

    int*      counters = (int*)d_ws;
    uint64_t* pairs    = (uint64_t*)((char*)d_ws + 65536);

    // capacity per bucket, bounded by workspace (ws ~2 GiB -> cap = 4096)
    int cap = (int)(((ws_size - 65536) / 8) / NBUCKETS);
    if (cap > 4096) cap = 4096;

    hipMemsetAsync(counters, 0, NBUCKETS * sizeof(int), stream);
    bin_pairs<<<GRID1, BLOCK1, 0, stream>>>(idx, in, counters, pairs, cap);
    accumulate<<<NBUCKETS, 256, 0, stream>>>(pairs, counters, out, cap);
}